// Round 13
// baseline (207.224 us; speedup 1.0000x reference)
//
#include <hip/hip_runtime.h>

// Correlation / cost-volume, fp32.
// corr[b, dy*9+dx, y, x] = (1/128) * sum_c in1[b,c,y,x] * in2[b,c,y+dy-4,x+dx-4]
//
// R20 = R17 (measured 84 us, VGPR 68, VALUBusy 35.7%) + depth-3 pipeline.
// Evidence chain: stall time is invariant at ~54 us (900 cyc/chunk) across
// barrier on/off (R17/R18) and load-layout (R19) => not convoy, not L1
// line consumption. It equals one far-L3/HBM round-trip per chunk: FETCH
// 65.5 MB = half the 128 MB unique first-touch per dispatch is HBM (~900
// cyc), rest L3 (~600). Depth-2 issues loads ~500 wall-cyc before use
// => ~400-900 cyc exposed every chunk. Fix: prefetch 2 chunks ahead
// (3 named stages, 6-chunk static rotation, no runtime stage index).
// Regs: 3x16 stage + ~36 overhead ~= 84-92 arch + 72 acc <= 170 cap.
// R19's split-row layout REVERTED (cost +15 us VALU, stall unchanged).
// Geometry unchanged: NT=576 zero-dead-lane (4ly x 9dy x 16xg), TY=4,
// grid 256 = 1 block/CU, 9 waves/CU, pacing s_barrier every 2 chunks
// (R17 vs R18 A/B: keeps working set L1-tight, 84 vs 90 us).

#define MAXD 4
#define ND 9
#define NDISP 81
#define BATCH 8
#define CH 128
#define HH 128
#define WW 128
#define HW (HH * WW)
#define NCHUNK CH                 // 1 channel per pipeline stage
#define TY 4
#define NT 576                    // 9 waves; every lane computes

__device__ __forceinline__ float dpp_shr1(float x) {   // lane i <- lane i-1 (row16)
    return __int_as_float(__builtin_amdgcn_update_dpp(
        0, __float_as_int(x), 0x111, 0xF, 0xF, true));
}
__device__ __forceinline__ float dpp_shl1(float x) {   // lane i <- lane i+1 (row16)
    return __int_as_float(__builtin_amdgcn_update_dpp(
        0, __float_as_int(x), 0x101, 0xF, 0xF, true));
}

__global__ __launch_bounds__(NT, 1) void corr_kernel(
    const float* __restrict__ in1,
    const float* __restrict__ in2,
    float* __restrict__ out)
{
    const int tid = threadIdx.x;
    const int b   = blockIdx.x;
    const int y0  = blockIdx.y * TY;
    const int xg  = tid & 15;               // 16 lanes span the 128-px row
    const int dy  = (tid >> 4) % ND;        // 9 dy groups
    const int ly  = tid / 144;              // 0..3: row within tile
    const int rl  = ly + dy;                // in2 row offset consumed (0..11)
    const bool rok = (unsigned)(y0 + rl - MAXD) < (unsigned)HH;
    int r2 = y0 + rl - MAXD;                // clamped row; garbage zeroed at end
    r2 = r2 < 0 ? 0 : (r2 > HH - 1 ? HH - 1 : r2);

    const float* p2 = in2 + (size_t)b * CH * HW + (size_t)r2 * WW + xg * 8;
    const float* p1 = in1 + (size_t)b * CH * HW + (size_t)(y0 + ly) * WW + xg * 8;

    float acc[ND][8];
    #pragma unroll
    for (int d = 0; d < ND; ++d)
        #pragma unroll
        for (int i = 0; i < 8; ++i) acc[d][i] = 0.0f;

    // 3 named pipeline stages (static indexing only -> registers, rule #20)
    float w0[8], a0[8], w1[8], a1[8], w2[8], a2[8];

    // load current chunk's 32B of in2 (w) and 32B of in1 (a); advance ptrs
    auto LD = [&](float* w, float* a) {
        float4 t0 = *(const float4*)(p2);
        float4 t1 = *(const float4*)(p2 + 4);
        float4 u0 = *(const float4*)(p1);
        float4 u1 = *(const float4*)(p1 + 4);
        w[0] = t0.x; w[1] = t0.y; w[2] = t0.z; w[3] = t0.w;
        w[4] = t1.x; w[5] = t1.y; w[6] = t1.z; w[7] = t1.w;
        a[0] = u0.x; a[1] = u0.y; a[2] = u0.z; a[3] = u0.w;
        a[4] = u1.x; a[5] = u1.y; a[6] = u1.z; a[7] = u1.w;
        p2 += HW; p1 += HW;
    };

    auto CMP = [&](const float* w, const float* a) {
        float W[16];
        W[0]  = dpp_shr1(w[4]);   // x-4..x-1 from lane-1; 0 at image edge
        W[1]  = dpp_shr1(w[5]);
        W[2]  = dpp_shr1(w[6]);
        W[3]  = dpp_shr1(w[7]);
        #pragma unroll
        for (int i = 0; i < 8; ++i) W[4 + i] = w[i];
        W[12] = dpp_shl1(w[0]);   // x+8..x+11 from lane+1; 0 at image edge
        W[13] = dpp_shl1(w[1]);
        W[14] = dpp_shl1(w[2]);
        W[15] = dpp_shl1(w[3]);
        #pragma unroll
        for (int d = 0; d < ND; ++d)
            #pragma unroll
            for (int i = 0; i < 8; ++i)
                acc[d][i] = fmaf(a[i], W[i + d], acc[d][i]);
    };

    // ---- depth-3 software pipeline: 6 chunks/iter, static stage rotation.
    // Every load is issued exactly 2 CMPs (2 chunks) before its use.
    LD(w0, a0);                   // chunk 0
    LD(w1, a1);                   // chunk 1
    #pragma unroll 1
    for (int k = 0; k <= NCHUNK - 8; k += 6) {   // k = 0,6,...,120
        LD(w2, a2);  CMP(w0, a0);                // load k+2, compute k
        LD(w0, a0);  CMP(w1, a1);                // load k+3, compute k+1
        asm volatile("s_barrier");               // pacing (R17 A/B-proven)
        LD(w1, a1);  CMP(w2, a2);                // load k+4, compute k+2
        LD(w2, a2);  CMP(w0, a0);                // load k+5, compute k+3
        asm volatile("s_barrier");
        LD(w0, a0);  CMP(w1, a1);                // load k+6, compute k+4
        LD(w1, a1);  CMP(w2, a2);                // load k+7, compute k+5
        asm volatile("s_barrier");
    }
    // tail: k=126,127 already loaded into w0/w1 by the last iteration
    CMP(w0, a0);
    CMP(w1, a1);

    // ---- epilogue: mean over C; OOB rows scale to exact zero ----
    const float sc = rok ? (1.0f / (float)CH) : 0.0f;
    float* outb = out + (size_t)b * NDISP * HW
                      + (size_t)(y0 + ly) * WW + xg * 8;
    #pragma unroll
    for (int d = 0; d < ND; ++d) {
        float* op = outb + (size_t)(dy * ND + d) * HW;
        float4 v0 = make_float4(acc[d][0] * sc, acc[d][1] * sc,
                                acc[d][2] * sc, acc[d][3] * sc);
        float4 v1 = make_float4(acc[d][4] * sc, acc[d][5] * sc,
                                acc[d][6] * sc, acc[d][7] * sc);
        *(float4*)(op)     = v0;
        *(float4*)(op + 4) = v1;
    }
}

extern "C" void kernel_launch(void* const* d_in, const int* in_sizes, int n_in,
                              void* d_out, int out_size, void* d_ws, size_t ws_size,
                              hipStream_t stream) {
    const float* in1 = (const float*)d_in[0];
    const float* in2 = (const float*)d_in[1];
    float* out = (float*)d_out;
    dim3 grid(BATCH, HH / TY);
    corr_kernel<<<grid, NT, 0, stream>>>(in1, in2, out);
}

// Round 17
// 206.390 us; speedup vs baseline: 1.0040x; 1.0040x over previous
//
#include <hip/hip_runtime.h>

// Correlation / cost-volume, fp32.
// corr[b, dy*9+dx, y, x] = (1/128) * sum_c in1[b,c,y,x] * in2[b,c,y+dy-4,x+dx-4]
//
// R24 = R22 resubmitted verbatim (broker timeouts R15/R16, never run).
// R22 = R17 (84 us) + in1 volume cut via wave0 reg-stage + ds_write.
// R21 FAILED correctness: its global_load_lds publish used a counted
// vmcnt whose safety depended on compiler instruction order, plus an
// under-drained prologue. Fix here: no global_load_lds. Wave0 loads in1
// chunks k+2,k+3 to REGISTERS at iteration top (latency hidden across
// the whole ~1500-cyc iteration), ds_writes them after the CMPs, and a
// uniform fused "s_waitcnt lgkmcnt(0); s_barrier" publishes: lgkmcnt
// counts the ds_writes themselves -- scheduling-independent, no vmcnt
// in the sync. in2's depth-2 register pipeline never drains.
//
// Volume theory (surviving after R18 barrier / R19 layout / R20 depth
// all left the ~54 us stall invariant): per chunk per CU the block
// issued 36 wave-VMEM instrs (36 KB) for 8 KB unique; in1 is 9x
// redundant across dy-groups. Now in1 = 2 wave-instrs/chunk (wave0),
// total 20/chunk; redundancy moves to LDS (ds_read_b128, 9 dy-groups
// broadcast same addr = free; xg 2-way aliasing = free per m136).
// LDS [2][2][512] dbuf = 8 KB; WAR: buffer written at end of iter k was
// last read in iter k-2, separated by the k-2 barrier (reads forced
// complete by CMP's data-use wait before that barrier).
// Geometry/in2/barrier cadence identical to R17: NT=576 zero-dead-lane,
// TY=4, grid 256 = 1 block/CU, 9 waves, launch_bounds(576,1).

#define MAXD 4
#define ND 9
#define NDISP 81
#define BATCH 8
#define CH 128
#define HH 128
#define WW 128
#define HW (HH * WW)
#define NCHUNK CH
#define TY 4
#define NT 576                    // 9 waves; every lane computes

__device__ __forceinline__ float dpp_shr1(float x) {   // lane i <- lane i-1 (row16)
    return __int_as_float(__builtin_amdgcn_update_dpp(
        0, __float_as_int(x), 0x111, 0xF, 0xF, true));
}
__device__ __forceinline__ float dpp_shl1(float x) {   // lane i <- lane i+1 (row16)
    return __int_as_float(__builtin_amdgcn_update_dpp(
        0, __float_as_int(x), 0x101, 0xF, 0xF, true));
}

// Publish barrier: lgkmcnt(0) completes this wave's ds_writes (wave0) /
// is a no-op for others (their ds_reads already drained by data use).
// Never touches vmcnt -> in2 prefetch stays in flight. "memory" stops
// the compiler moving LDS ops across it.
#define PUBBAR() asm volatile( \
    "s_waitcnt lgkmcnt(0)\n\ts_barrier" ::: "memory")

__global__ __launch_bounds__(NT, 1) void corr_kernel(
    const float* __restrict__ in1,
    const float* __restrict__ in2,
    float* __restrict__ out)
{
    __shared__ float s1[2][2][TY * WW];     // [buf][slot][512] = 8 KB

    const int tid = threadIdx.x;
    const int b   = blockIdx.x;
    const int y0  = blockIdx.y * TY;
    const int xg  = tid & 15;               // 16 lanes span the 128-px row
    const int dy  = (tid >> 4) % ND;        // 9 dy groups
    const int ly  = tid / 144;              // 0..3: row within tile
    const int rl  = ly + dy;                // in2 row offset consumed (0..11)
    const bool rok = (unsigned)(y0 + rl - MAXD) < (unsigned)HH;
    int r2 = y0 + rl - MAXD;                // clamped row; garbage zeroed at end
    r2 = r2 < 0 ? 0 : (r2 > HH - 1 ? HH - 1 : r2);

    const float* p2 = in2 + (size_t)b * CH * HW + (size_t)r2 * WW + xg * 8;

    const int wv   = __builtin_amdgcn_readfirstlane(tid >> 6);   // 0..8
    const int lane = tid & 63;
    // wave0 in1 source: chunk c rows y0..y0+3 are 512 contiguous floats
    const float* p1w = in1 + (size_t)b * CH * HW + (size_t)y0 * WW + lane * 8;

    const int aoff = ly * WW + xg * 8;      // thread's in1 slice within a slot

    float acc[ND][8];
    #pragma unroll
    for (int d = 0; d < ND; ++d)
        #pragma unroll
        for (int i = 0; i < 8; ++i) acc[d][i] = 0.0f;

    float w0[8], w1[8];

    auto LDW = [&](float* w) {              // in2 stage load, 32 B/lane
        float4 t0 = *(const float4*)(p2);
        float4 t1 = *(const float4*)(p2 + 4);
        w[0] = t0.x; w[1] = t0.y; w[2] = t0.z; w[3] = t0.w;
        w[4] = t1.x; w[5] = t1.y; w[6] = t1.z; w[7] = t1.w;
        p2 += HW;
    };
    auto LDA = [&](int c, float* a) {       // in1 from LDS, 2x ds_read_b128
        const float* ap = &s1[(c >> 1) & 1][c & 1][aoff];
        float4 u0 = *(const float4*)(ap);
        float4 u1 = *(const float4*)(ap + 4);
        a[0] = u0.x; a[1] = u0.y; a[2] = u0.z; a[3] = u0.w;
        a[4] = u1.x; a[5] = u1.y; a[6] = u1.z; a[7] = u1.w;
    };
    auto CMP = [&](const float* w, const float* a) {
        float W[16];
        W[0]  = dpp_shr1(w[4]);   // x-4..x-1 from lane-1; 0 at image edge
        W[1]  = dpp_shr1(w[5]);
        W[2]  = dpp_shr1(w[6]);
        W[3]  = dpp_shr1(w[7]);
        #pragma unroll
        for (int i = 0; i < 8; ++i) W[4 + i] = w[i];
        W[12] = dpp_shl1(w[0]);   // x+8..x+11 from lane+1; 0 at image edge
        W[13] = dpp_shl1(w[1]);
        W[14] = dpp_shl1(w[2]);
        W[15] = dpp_shl1(w[3]);
        #pragma unroll
        for (int d = 0; d < ND; ++d)
            #pragma unroll
            for (int i = 0; i < 8; ++i)
                acc[d][i] = fmaf(a[i], W[i + d], acc[d][i]);
    };

    // ---- prologue: wave0 stages in1 chunks 0,1 -> buf0; publish ----
    if (wv == 0) {
        const float* g0 = p1w;                       // chunk 0
        const float* g1 = p1w + HW;                  // chunk 1
        float4 t0 = *(const float4*)(g0);
        float4 t1 = *(const float4*)(g0 + 4);
        float4 t2 = *(const float4*)(g1);
        float4 t3 = *(const float4*)(g1 + 4);
        float* l0 = &s1[0][0][lane * 8];
        *(float4*)(l0)     = t0;
        *(float4*)(l0 + 4) = t1;
        float* l1 = &s1[0][1][lane * 8];
        *(float4*)(l1)     = t2;
        *(float4*)(l1 + 4) = t3;
    }
    LDW(w0);                                         // in2 chunk 0
    PUBBAR();

    #pragma unroll 1
    for (int k = 0; k < NCHUNK; k += 2) {
        const bool pf = (k + 2 < NCHUNK);
        float4 t0, t1, t2, t3;
        if (wv == 0 && pf) {                         // issue in1 k+2,k+3 early
            const float* g0 = p1w + (size_t)(k + 2) * HW;
            const float* g1 = p1w + (size_t)(k + 3) * HW;
            t0 = *(const float4*)(g0);
            t1 = *(const float4*)(g0 + 4);
            t2 = *(const float4*)(g1);
            t3 = *(const float4*)(g1 + 4);
        }

        float A0[8], A1[8];
        LDA(k, A0);
        LDA(k + 1, A1);
        LDW(w1);                                     // in2 chunk k+1
        CMP(w0, A0);                                 // chunk k
        if (pf) LDW(w0);                             // in2 chunk k+2
        CMP(w1, A1);                                 // chunk k+1

        if (wv == 0 && pf) {                         // write late (T14 split)
            const int nb = ((k + 2) >> 1) & 1;       // other buffer
            float* l0 = &s1[nb][0][lane * 8];
            *(float4*)(l0)     = t0;
            *(float4*)(l0 + 4) = t1;
            float* l1 = &s1[nb][1][lane * 8];
            *(float4*)(l1)     = t2;
            *(float4*)(l1 + 4) = t3;
        }
        PUBBAR();                                    // publish buf for k+2,k+3
    }

    // ---- epilogue: mean over C; OOB in2 rows scale to exact zero ----
    const float sc = rok ? (1.0f / (float)CH) : 0.0f;
    float* outb = out + (size_t)b * NDISP * HW
                      + (size_t)(y0 + ly) * WW + xg * 8;
    #pragma unroll
    for (int d = 0; d < ND; ++d) {
        float* op = outb + (size_t)(dy * ND + d) * HW;
        float4 v0 = make_float4(acc[d][0] * sc, acc[d][1] * sc,
                                acc[d][2] * sc, acc[d][3] * sc);
        float4 v1 = make_float4(acc[d][4] * sc, acc[d][5] * sc,
                                acc[d][6] * sc, acc[d][7] * sc);
        *(float4*)(op)     = v0;
        *(float4*)(op + 4) = v1;
    }
}

extern "C" void kernel_launch(void* const* d_in, const int* in_sizes, int n_in,
                              void* d_out, int out_size, void* d_ws, size_t ws_size,
                              hipStream_t stream) {
    const float* in1 = (const float*)d_in[0];
    const float* in2 = (const float*)d_in[1];
    float* out = (float*)d_out;
    dim3 grid(BATCH, HH / TY);
    corr_kernel<<<grid, NT, 0, stream>>>(in1, in2, out);
}